// Round 1
// 230.845 us; speedup vs baseline: 1.0006x; 1.0006x over previous
//
#include <hip/hip_runtime.h>
#include <math.h>

#define HPX 128
#define WPX 128
#define HW  16384          // H*W
#define CCH 16             // channels
#define NLINES 81920       // 5 * H * W
#define NPTS 32
#define LOI_SIZE (NLINES * 512)   // 41,943,040 floats
#define SORT_N 8192
#define NBINS 4096
#define CAND 1024

// workspace layout (bytes)
#define FEAT_T_OFF 0                             // 1,048,576
#define LINES_OFF  1048576                       // 81920*16 = 1,310,720
#define KEYS_OFF   (1048576 + 1310720)           // 65,536
#define HIST_OFF   (KEYS_OFF + 65536)            // 16,384
#define CTR_OFF    (HIST_OFF + 16384)            // 4

// ---------------------------------------------------------------------------
// features (C,H,W) -> feat_t (H*W, C)
// ---------------------------------------------------------------------------
__global__ __launch_bounds__(256) void transpose_feat(
        const float* __restrict__ feat, float* __restrict__ feat_t) {
    int tid = blockIdx.x * 256 + threadIdx.x;   // 0 .. 262143
    int pix = tid >> 4;
    int c   = tid & 15;
    feat_t[tid] = feat[c * HW + pix];
}

// ---------------------------------------------------------------------------
// Per-line endpoint decode (all trig lives here, 81920 threads only).
// lines[line] = (xs, ys, xe, ye)
// ---------------------------------------------------------------------------
__global__ __launch_bounds__(256) void lines_kernel(
        const float* __restrict__ md,
        const float* __restrict__ dis,
        const float* __restrict__ res,
        float4* __restrict__ lines) {
    int line = blockIdx.x * 256 + threadIdx.x;   // 0 .. 81919
    int r    = line >> 14;        // 0..4
    int pix  = line & (HW - 1);
    int y0i  = pix >> 7, x0i = pix & 127;

    float md0 = md[pix], md1 = md[HW + pix], md2 = md[2 * HW + pix];
    float dv  = dis[pix], rv = res[pix];

    float dist = fminf(fmaxf(dv + rv * ((float)r - 2.0f), 0.0f), 1.0f);
    float d5   = dist * 5.0f;
    float md_un = (md0 - 0.5f) * 6.28318530717958647692f;
    float cs = cosf(md_un), ss = sinf(md_un);
    float y_st = tanf(md1 * 1.57079632679489661923f);
    float y_ed = tanf(-md2 * 1.57079632679489661923f);

    float x0f = (float)x0i, y0f = (float)y0i;
    float4 ep;
    ep.x = fminf(fmaxf((cs - ss * y_st) * d5 + x0f, 0.0f), 127.0f);  // xs
    ep.y = fminf(fmaxf((ss + cs * y_st) * d5 + y0f, 0.0f), 127.0f);  // ys
    ep.z = fminf(fmaxf((cs - ss * y_ed) * d5 + x0f, 0.0f), 127.0f);  // xe
    ep.w = fminf(fmaxf((ss + cs * y_ed) * d5 + y0f, 0.0f), 127.0f);  // ye
    lines[line] = ep;
}

// ---------------------------------------------------------------------------
// 3x3 NMS + compact survivors + 4096-bin value histogram.
// key = float_bits(val)<<32 | (0xFFFFFFFF - idx)  (desc sort => topk order)
// ---------------------------------------------------------------------------
__global__ __launch_bounds__(256) void nms_compact(
        const float* __restrict__ jloc,
        unsigned long long* __restrict__ keys,
        unsigned int* __restrict__ hist,
        unsigned int* __restrict__ ctr) {
    int pix = blockIdx.x * 256 + threadIdx.x;
    if (pix >= HW) return;
    int y = pix >> 7, x = pix & 127;
    float a = jloc[pix];
    float m = a;
    #pragma unroll
    for (int dy = -1; dy <= 1; dy++) {
        #pragma unroll
        for (int dx = -1; dx <= 1; dx++) {
            int yy = y + dy, xx = x + dx;
            if (yy >= 0 && yy < HPX && xx >= 0 && xx < WPX) {
                m = fmaxf(m, jloc[yy * WPX + xx]);
            }
        }
    }
    if (a == m && a > 0.0f) {
        unsigned int slot = atomicAdd(ctr, 1u);
        if (slot < SORT_N) {
            unsigned int bits = __float_as_uint(a);
            keys[slot] = ((unsigned long long)bits << 32)
                       | (unsigned long long)(0xFFFFFFFFu - (unsigned int)pix);
        }
        int bin = min(NBINS - 1, (int)(a * (float)NBINS));
        atomicAdd(&hist[bin], 1u);
    }
}

// ---------------------------------------------------------------------------
// Single-block top-k: suffix-scan histogram -> threshold bin T -> compact
// candidates (bin >= T, guaranteed >= topk of them) -> bitonic sort 1024 ->
// emit junctions + scores.
// ---------------------------------------------------------------------------
__global__ __launch_bounds__(1024) void select_topk(
        const unsigned long long* __restrict__ keys_g,
        const unsigned int* __restrict__ ctr,
        const unsigned int* __restrict__ hist,
        const float* __restrict__ joff,
        float* __restrict__ junc, float* __restrict__ scores, int topk) {
    __shared__ unsigned int h[NBINS];            // 16 KB
    __shared__ unsigned long long cand[CAND];    // 8 KB
    __shared__ unsigned int scount;
    __shared__ int Ts;
    int t = threadIdx.x;

    #pragma unroll
    for (int r = 0; r < 4; r++) h[t + r * 1024] = hist[t + r * 1024];
    if (t == 0) { scount = 0; Ts = 0; }
    __syncthreads();

    // suffix sum: h[b] := sum_{b' >= b} h[b']   (Hillis-Steele, 12 passes)
    for (int off = 1; off < NBINS; off <<= 1) {
        unsigned int v[4];
        #pragma unroll
        for (int r = 0; r < 4; r++) {
            int i = t + r * 1024;
            v[r] = (i + off < NBINS) ? h[i + off] : 0u;
        }
        __syncthreads();
        #pragma unroll
        for (int r = 0; r < 4; r++) h[t + r * 1024] += v[r];
        __syncthreads();
    }

    // threshold bin T: h[T] >= topk, h[T+1] < topk (unique crossing)
    #pragma unroll
    for (int r = 0; r < 4; r++) {
        int b = t + r * 1024;
        unsigned int sb = h[b];
        unsigned int sn = (b + 1 < NBINS) ? h[b + 1] : 0u;
        if (sb >= (unsigned int)topk && sn < (unsigned int)topk) Ts = b;
    }
    __syncthreads();
    int T = Ts;

    // compact candidates
    int n = min(ctr[0], (unsigned int)SORT_N);
    for (int i = t; i < n; i += 1024) {
        unsigned long long kk = keys_g[i];
        float val = __uint_as_float((unsigned int)(kk >> 32));
        int bin = min(NBINS - 1, (int)(val * (float)NBINS));
        if (bin >= T) {
            unsigned int p = atomicAdd(&scount, 1u);
            if (p < CAND) cand[p] = kk;
        }
    }
    __syncthreads();
    unsigned int sc = min(scount, (unsigned int)CAND);
    if (t >= (int)sc) cand[t] = 0ull;           // pad
    __syncthreads();

    // bitonic sort 1024 descending
    for (int k = 2; k <= CAND; k <<= 1) {
        for (int j = k >> 1; j > 0; j >>= 1) {
            int ixj = t ^ j;
            if (ixj > t) {
                unsigned long long a = cand[t], b = cand[ixj];
                bool desc = ((t & k) == 0);
                if (desc ? (a < b) : (a > b)) { cand[t] = b; cand[ixj] = a; }
            }
            __syncthreads();
        }
    }

    if (t < topk) {
        unsigned long long kk = cand[t];
        float val = __uint_as_float((unsigned int)(kk >> 32));
        unsigned int idx = 0xFFFFFFFFu - (unsigned int)(kk & 0xFFFFFFFFull);
        if (idx >= HW) idx = 0;                  // pad guard (unreachable here)
        float xo = joff[idx];
        float yo = joff[HW + idx];
        junc[2 * t]     = (float)(idx & 127) + xo + 0.5f;
        junc[2 * t + 1] = (float)(idx >> 7)  + yo + 0.5f;
        scores[t] = val;
    }
}

// ---------------------------------------------------------------------------
// LOI v2: one thread = (line, point, channel-quad).
// 4 consecutive lanes (cq=0..3) gather the SAME bilinear corner -> the
// coalescer merges them into one 64B segment (4x fewer divergent address
// lookups than v1's one-thread-per-(line,kq) layout).
// Output stores are non-temporal so the 167.8 MB stream does not evict the
// 1 MB feat_t working set from L2.
// ---------------------------------------------------------------------------
__global__ __launch_bounds__(256) void loi_kernel(
        const float4* __restrict__ lines,
        const float4* __restrict__ feat4,     // feat_t viewed as float4[pix*4+cq]
        float* __restrict__ out) {
    int tid  = blockIdx.x * 256 + threadIdx.x;   // 0 .. 10,485,759
    int cq   = tid & 3;                          // channel quad 0..3
    int p    = (tid >> 2) & 31;                  // sample point 0..31
    int line = tid >> 7;                         // 0 .. 81919

    float4 ep = lines[line];                     // broadcast within wave

    float tk = (float)p * (1.0f / 31.0f);
    float px = ep.x * tk + ep.z * (1.0f - tk) - 0.5f;
    float py = ep.y * tk + ep.w * (1.0f - tk) - 0.5f;

    float px0 = fminf(fmaxf(floorf(px), 0.0f), 127.0f);
    float py0 = fminf(fmaxf(floorf(py), 0.0f), 127.0f);
    float px1 = fminf(px0 + 1.0f, 127.0f);
    float py1 = fminf(py0 + 1.0f, 127.0f);

    float wx1 = px - px0, wx0 = px1 - px;
    float wy1 = py - py0, wy0 = py1 - py;
    float w00 = wy0 * wx0, w01 = wy0 * wx1;
    float w10 = wy1 * wx0, w11 = wy1 * wx1;

    int r0 = ((int)py0) * WPX;
    int r1 = ((int)py1) * WPX;
    int c0 = (int)px0;
    int c1 = (int)px1;

    // 4 lanes x 16B = one fully-coalesced 64B corner line each
    float4 a = feat4[(r0 + c0) * 4 + cq];
    float4 b = feat4[(r0 + c1) * 4 + cq];
    float4 c = feat4[(r1 + c0) * 4 + cq];
    float4 d = feat4[(r1 + c1) * 4 + cq];

    float v0 = a.x * w00 + b.x * w01 + c.x * w10 + d.x * w11;
    float v1 = a.y * w00 + b.y * w01 + c.y * w10 + d.y * w11;
    float v2 = a.z * w00 + b.z * w01 + c.z * w10 + d.z * w11;
    float v3 = a.w * w00 + b.w * w01 + c.w * w10 + d.w * w11;

    // out[line*512 + c*32 + p], c = cq*4 + j.  Per store instruction a wave
    // covers 4 full 64B segments (16 lanes x 4B contiguous per cq group).
    float* ob = out + (size_t)line * 512 + cq * 128 + p;
    __builtin_nontemporal_store(v0, ob);
    __builtin_nontemporal_store(v1, ob + 32);
    __builtin_nontemporal_store(v2, ob + 64);
    __builtin_nontemporal_store(v3, ob + 96);
}

extern "C" void kernel_launch(void* const* d_in, const int* in_sizes, int n_in,
                              void* d_out, int out_size, void* d_ws, size_t ws_size,
                              hipStream_t stream) {
    const float* md   = (const float*)d_in[0];
    const float* dis  = (const float*)d_in[1];
    const float* res  = (const float*)d_in[2];
    const float* feat = (const float*)d_in[3];
    const float* jloc = (const float*)d_in[4];
    const float* joff = (const float*)d_in[5];
    int topk = (out_size - LOI_SIZE) / 3;

    char* ws = (char*)d_ws;
    float* feat_t             = (float*)(ws + FEAT_T_OFF);
    float4* lines             = (float4*)(ws + LINES_OFF);
    unsigned long long* keys  = (unsigned long long*)(ws + KEYS_OFF);
    unsigned int* hist        = (unsigned int*)(ws + HIST_OFF);
    unsigned int* ctr         = (unsigned int*)(ws + CTR_OFF);

    float* out    = (float*)d_out;
    float* junc   = out + LOI_SIZE;
    float* scores = junc + 2 * topk;

    // zero hist + ctr (contiguous)
    hipMemsetAsync(ws + HIST_OFF, 0, NBINS * 4 + 4, stream);

    transpose_feat<<<(HW * CCH) / 256, 256, 0, stream>>>(feat, feat_t);
    lines_kernel <<<NLINES / 256,      256, 0, stream>>>(md, dis, res, lines);
    nms_compact  <<<HW / 256,          256, 0, stream>>>(jloc, keys, hist, ctr);
    select_topk  <<<1,                1024, 0, stream>>>(keys, ctr, hist, joff, junc, scores, topk);
    // one thread per (line, point, channel-quad): NLINES*32*4 threads
    loi_kernel   <<<(NLINES * 128) / 256, 256, 0, stream>>>(
                     lines, (const float4*)feat_t, out);
}

// Round 2
// 218.428 us; speedup vs baseline: 1.0574x; 1.0568x over previous
//
#include <hip/hip_runtime.h>
#include <math.h>

#define HPX 128
#define WPX 128
#define HW  16384          // H*W
#define CCH 16             // channels
#define NLINES 81920       // 5 * H * W
#define NPTS 32
#define LOI_SIZE (NLINES * 512)   // 41,943,040 floats
#define SORT_N 8192
#define NBINS 4096
#define CAND 1024
#define PREP_TRANS (HW * CCH)     // 262144 transpose work-items

// workspace layout (bytes)
#define FEAT_T_OFF 0                             // 1,048,576
#define LINES_OFF  1048576                       // 81920*16 = 1,310,720
#define KEYS_OFF   (1048576 + 1310720)           // 65,536
#define HIST_OFF   (KEYS_OFF + 65536)            // 16,384
#define CTR_OFF    (HIST_OFF + 16384)            // 4

// ---------------------------------------------------------------------------
// Fused prep: features (C,H,W) -> feat_t (H*W, C), per-line endpoint decode,
// and hist/ctr zeroing (stream order guarantees visibility to nms_compact).
// ---------------------------------------------------------------------------
__global__ __launch_bounds__(256) void prep_kernel(
        const float* __restrict__ feat, float* __restrict__ feat_t,
        const float* __restrict__ md,
        const float* __restrict__ dis,
        const float* __restrict__ res,
        float4* __restrict__ lines,
        unsigned int* __restrict__ hist,
        unsigned int* __restrict__ ctr) {
    int tid = blockIdx.x * 256 + threadIdx.x;   // 0 .. 344063

    if (tid < NBINS) hist[tid] = 0u;
    if (tid == NBINS) ctr[0] = 0u;

    if (tid < PREP_TRANS) {
        int pix = tid >> 4;
        int c   = tid & 15;
        feat_t[tid] = feat[c * HW + pix];
    } else {
        int line = tid - PREP_TRANS;             // 0 .. 81919
        int r    = line >> 14;                   // 0..4
        int pix  = line & (HW - 1);
        int y0i  = pix >> 7, x0i = pix & 127;

        float md0 = md[pix], md1 = md[HW + pix], md2 = md[2 * HW + pix];
        float dv  = dis[pix], rv = res[pix];

        float dist = fminf(fmaxf(dv + rv * ((float)r - 2.0f), 0.0f), 1.0f);
        float d5   = dist * 5.0f;
        float md_un = (md0 - 0.5f) * 6.28318530717958647692f;
        float cs = cosf(md_un), ss = sinf(md_un);
        float y_st = tanf(md1 * 1.57079632679489661923f);
        float y_ed = tanf(-md2 * 1.57079632679489661923f);

        float x0f = (float)x0i, y0f = (float)y0i;
        float4 ep;
        ep.x = fminf(fmaxf((cs - ss * y_st) * d5 + x0f, 0.0f), 127.0f);  // xs
        ep.y = fminf(fmaxf((ss + cs * y_st) * d5 + y0f, 0.0f), 127.0f);  // ys
        ep.z = fminf(fmaxf((cs - ss * y_ed) * d5 + x0f, 0.0f), 127.0f);  // xe
        ep.w = fminf(fmaxf((ss + cs * y_ed) * d5 + y0f, 0.0f), 127.0f);  // ye
        lines[line] = ep;
    }
}

// ---------------------------------------------------------------------------
// 3x3 NMS + compact survivors + 4096-bin value histogram.
// key = float_bits(val)<<32 | (0xFFFFFFFF - idx)  (desc order => topk order;
// keys are unique since idx is unique, so rank is a bijection)
// ---------------------------------------------------------------------------
__global__ __launch_bounds__(256) void nms_compact(
        const float* __restrict__ jloc,
        unsigned long long* __restrict__ keys,
        unsigned int* __restrict__ hist,
        unsigned int* __restrict__ ctr) {
    int pix = blockIdx.x * 256 + threadIdx.x;
    if (pix >= HW) return;
    int y = pix >> 7, x = pix & 127;
    float a = jloc[pix];
    float m = a;
    #pragma unroll
    for (int dy = -1; dy <= 1; dy++) {
        #pragma unroll
        for (int dx = -1; dx <= 1; dx++) {
            int yy = y + dy, xx = x + dx;
            if (yy >= 0 && yy < HPX && xx >= 0 && xx < WPX) {
                m = fmaxf(m, jloc[yy * WPX + xx]);
            }
        }
    }
    if (a == m && a > 0.0f) {
        unsigned int slot = atomicAdd(ctr, 1u);
        if (slot < SORT_N) {
            unsigned int bits = __float_as_uint(a);
            keys[slot] = ((unsigned long long)bits << 32)
                       | (unsigned long long)(0xFFFFFFFFu - (unsigned int)pix);
        }
        int bin = min(NBINS - 1, (int)(a * (float)NBINS));
        atomicAdd(&hist[bin], 1u);
    }
}

// ---------------------------------------------------------------------------
// Single-block top-k v2: suffix-scan histogram -> threshold bin T ->
// compact candidates (bin >= T, ~topk+delta of them) -> RANK-based selection
// (rank r = #{keys > k}, unique keys => bijection => direct write to slot r).
// Replaces the 55-barrier bitonic sort with ~4 barriers.
// ---------------------------------------------------------------------------
__global__ __launch_bounds__(1024) void select_topk(
        const unsigned long long* __restrict__ keys_g,
        const unsigned int* __restrict__ ctr,
        const unsigned int* __restrict__ hist,
        const float* __restrict__ joff,
        float* __restrict__ junc, float* __restrict__ scores, int topk) {
    __shared__ unsigned int h[NBINS];            // 16 KB
    __shared__ unsigned long long cand[CAND];    // 8 KB
    __shared__ unsigned int scount;
    __shared__ int Ts;
    int t = threadIdx.x;

    #pragma unroll
    for (int r = 0; r < 4; r++) h[t + r * 1024] = hist[t + r * 1024];
    if (t == 0) { scount = 0; Ts = 0; }
    __syncthreads();

    // suffix sum: h[b] := sum_{b' >= b} h[b']   (Hillis-Steele, 12 passes)
    for (int off = 1; off < NBINS; off <<= 1) {
        unsigned int v[4];
        #pragma unroll
        for (int r = 0; r < 4; r++) {
            int i = t + r * 1024;
            v[r] = (i + off < NBINS) ? h[i + off] : 0u;
        }
        __syncthreads();
        #pragma unroll
        for (int r = 0; r < 4; r++) h[t + r * 1024] += v[r];
        __syncthreads();
    }

    // threshold bin T: h[T] >= topk, h[T+1] < topk (unique crossing)
    #pragma unroll
    for (int r = 0; r < 4; r++) {
        int b = t + r * 1024;
        unsigned int sb = h[b];
        unsigned int sn = (b + 1 < NBINS) ? h[b + 1] : 0u;
        if (sb >= (unsigned int)topk && sn < (unsigned int)topk) Ts = b;
    }
    __syncthreads();
    int T = Ts;

    // compact candidates with bin >= T (count is >= topk, typically topk+~10)
    int n = min(ctr[0], (unsigned int)SORT_N);
    for (int i = t; i < n; i += 1024) {
        unsigned long long kk = keys_g[i];
        float val = __uint_as_float((unsigned int)(kk >> 32));
        int bin = min(NBINS - 1, (int)(val * (float)NBINS));
        if (bin >= T) {
            unsigned int p = atomicAdd(&scount, 1u);
            if (p < CAND) cand[p] = kk;
        }
    }
    __syncthreads();
    unsigned int sc = min(scount, (unsigned int)CAND);

    // rank-based selection: slot r = #{cand > mine}; keys unique => bijection
    if (t < (int)sc) {
        unsigned long long k = cand[t];
        int r = 0;
        for (unsigned int j = 0; j < sc; j++) r += (cand[j] > k) ? 1 : 0;
        if (r < topk) {
            float val = __uint_as_float((unsigned int)(k >> 32));
            unsigned int idx = 0xFFFFFFFFu - (unsigned int)(k & 0xFFFFFFFFull);
            if (idx >= HW) idx = 0;              // pad guard (unreachable)
            float xo = joff[idx];
            float yo = joff[HW + idx];
            junc[2 * r]     = (float)(idx & 127) + xo + 0.5f;
            junc[2 * r + 1] = (float)(idx >> 7)  + yo + 0.5f;
            scores[r] = val;
        }
    }
    // pad slots [sc, topk) -- replicates old zero-key pad path (unreachable
    // in practice: sc >= topk by construction of T when enough survivors)
    if (t >= (int)sc && t < topk) {
        junc[2 * t]     = joff[0] + 0.5f;
        junc[2 * t + 1] = joff[HW] + 0.5f;
        scores[t] = 0.0f;
    }
}

// ---------------------------------------------------------------------------
// LOI: one thread = (line, point, channel-quad).
// 4 consecutive lanes (cq=0..3) gather the SAME bilinear corner -> one 64B
// segment per 4 lanes. Non-temporal output stores keep the 167.8 MB stream
// from evicting the 1 MB feat_t working set out of L2.
// ---------------------------------------------------------------------------
__global__ __launch_bounds__(256) void loi_kernel(
        const float4* __restrict__ lines,
        const float4* __restrict__ feat4,     // feat_t viewed as float4[pix*4+cq]
        float* __restrict__ out) {
    int tid  = blockIdx.x * 256 + threadIdx.x;   // 0 .. 10,485,759
    int cq   = tid & 3;                          // channel quad 0..3
    int p    = (tid >> 2) & 31;                  // sample point 0..31
    int line = tid >> 7;                         // 0 .. 81919

    float4 ep = lines[line];                     // broadcast within wave

    float tk = (float)p * (1.0f / 31.0f);
    float px = ep.x * tk + ep.z * (1.0f - tk) - 0.5f;
    float py = ep.y * tk + ep.w * (1.0f - tk) - 0.5f;

    float px0 = fminf(fmaxf(floorf(px), 0.0f), 127.0f);
    float py0 = fminf(fmaxf(floorf(py), 0.0f), 127.0f);
    float px1 = fminf(px0 + 1.0f, 127.0f);
    float py1 = fminf(py0 + 1.0f, 127.0f);

    float wx1 = px - px0, wx0 = px1 - px;
    float wy1 = py - py0, wy0 = py1 - py;
    float w00 = wy0 * wx0, w01 = wy0 * wx1;
    float w10 = wy1 * wx0, w11 = wy1 * wx1;

    int r0 = ((int)py0) * WPX;
    int r1 = ((int)py1) * WPX;
    int c0 = (int)px0;
    int c1 = (int)px1;

    float4 a = feat4[(r0 + c0) * 4 + cq];
    float4 b = feat4[(r0 + c1) * 4 + cq];
    float4 c = feat4[(r1 + c0) * 4 + cq];
    float4 d = feat4[(r1 + c1) * 4 + cq];

    float v0 = a.x * w00 + b.x * w01 + c.x * w10 + d.x * w11;
    float v1 = a.y * w00 + b.y * w01 + c.y * w10 + d.y * w11;
    float v2 = a.z * w00 + b.z * w01 + c.z * w10 + d.z * w11;
    float v3 = a.w * w00 + b.w * w01 + c.w * w10 + d.w * w11;

    // out[line*512 + c*32 + p], c = cq*4 + j.  Per store instruction a wave
    // covers 4 full 64B segments (16 lanes x 4B contiguous per cq group).
    float* ob = out + (size_t)line * 512 + cq * 128 + p;
    __builtin_nontemporal_store(v0, ob);
    __builtin_nontemporal_store(v1, ob + 32);
    __builtin_nontemporal_store(v2, ob + 64);
    __builtin_nontemporal_store(v3, ob + 96);
}

extern "C" void kernel_launch(void* const* d_in, const int* in_sizes, int n_in,
                              void* d_out, int out_size, void* d_ws, size_t ws_size,
                              hipStream_t stream) {
    const float* md   = (const float*)d_in[0];
    const float* dis  = (const float*)d_in[1];
    const float* res  = (const float*)d_in[2];
    const float* feat = (const float*)d_in[3];
    const float* jloc = (const float*)d_in[4];
    const float* joff = (const float*)d_in[5];
    int topk = (out_size - LOI_SIZE) / 3;

    char* ws = (char*)d_ws;
    float* feat_t             = (float*)(ws + FEAT_T_OFF);
    float4* lines             = (float4*)(ws + LINES_OFF);
    unsigned long long* keys  = (unsigned long long*)(ws + KEYS_OFF);
    unsigned int* hist        = (unsigned int*)(ws + HIST_OFF);
    unsigned int* ctr         = (unsigned int*)(ws + CTR_OFF);

    float* out    = (float*)d_out;
    float* junc   = out + LOI_SIZE;
    float* scores = junc + 2 * topk;

    // 4 dispatches total (was 6: memset + 5 kernels)
    prep_kernel <<<(PREP_TRANS + NLINES) / 256, 256, 0, stream>>>(
                    feat, feat_t, md, dis, res, lines, hist, ctr);
    nms_compact <<<HW / 256, 256, 0, stream>>>(jloc, keys, hist, ctr);
    select_topk <<<1, 1024, 0, stream>>>(keys, ctr, hist, joff, junc, scores, topk);
    loi_kernel  <<<(NLINES * 128) / 256, 256, 0, stream>>>(
                    lines, (const float4*)feat_t, out);
}

// Round 3
// 215.699 us; speedup vs baseline: 1.0708x; 1.0127x over previous
//
#include <hip/hip_runtime.h>
#include <math.h>

#define HPX 128
#define WPX 128
#define HW  16384          // H*W
#define CCH 16             // channels
#define NLINES 81920       // 5 * H * W
#define NPTS 32
#define LOI_SIZE (NLINES * 512)   // 41,943,040 floats
#define NBINS 4096
#define CAND 1024
#define PREP_TRANS (HW * CCH)     // 262144 transpose work-items
#define PREP_TOTAL (PREP_TRANS + NLINES + HW)   // 360448

// workspace layout (bytes)
#define FEAT_T_OFF 0                             // 1,048,576
#define LINES_OFF  1048576                       // 81920*16 = 1,310,720
#define KEYS_OFF   (1048576 + 1310720)           // 16384*8 = 131,072

// ---------------------------------------------------------------------------
// Fused prep: features (C,H,W) -> feat_t (H*W, C), per-line endpoint decode,
// AND 3x3 NMS as a pure per-pixel map: keys_full[pix] = survivor ? key : 0.
// key = float_bits(val)<<32 | (0xFFFFFFFF - pix)  (unique keys, desc order
// == topk order). No atomics, no counter, no global histogram -> no ordering
// hazard, so all three fuse into one dispatch.
// ---------------------------------------------------------------------------
__global__ __launch_bounds__(256) void prep_kernel(
        const float* __restrict__ feat, float* __restrict__ feat_t,
        const float* __restrict__ md,
        const float* __restrict__ dis,
        const float* __restrict__ res,
        float4* __restrict__ lines,
        const float* __restrict__ jloc,
        unsigned long long* __restrict__ keys_full) {
    int tid = blockIdx.x * 256 + threadIdx.x;   // 0 .. PREP_TOTAL-1

    if (tid < PREP_TRANS) {
        int pix = tid >> 4;
        int c   = tid & 15;
        feat_t[tid] = feat[c * HW + pix];
    } else if (tid < PREP_TRANS + NLINES) {
        int line = tid - PREP_TRANS;             // 0 .. 81919
        int r    = line >> 14;                   // 0..4
        int pix  = line & (HW - 1);
        int y0i  = pix >> 7, x0i = pix & 127;

        float md0 = md[pix], md1 = md[HW + pix], md2 = md[2 * HW + pix];
        float dv  = dis[pix], rv = res[pix];

        float dist = fminf(fmaxf(dv + rv * ((float)r - 2.0f), 0.0f), 1.0f);
        float d5   = dist * 5.0f;
        float md_un = (md0 - 0.5f) * 6.28318530717958647692f;
        float cs = cosf(md_un), ss = sinf(md_un);
        float y_st = tanf(md1 * 1.57079632679489661923f);
        float y_ed = tanf(-md2 * 1.57079632679489661923f);

        float x0f = (float)x0i, y0f = (float)y0i;
        float4 ep;
        ep.x = fminf(fmaxf((cs - ss * y_st) * d5 + x0f, 0.0f), 127.0f);  // xs
        ep.y = fminf(fmaxf((ss + cs * y_st) * d5 + y0f, 0.0f), 127.0f);  // ys
        ep.z = fminf(fmaxf((cs - ss * y_ed) * d5 + x0f, 0.0f), 127.0f);  // xe
        ep.w = fminf(fmaxf((ss + cs * y_ed) * d5 + y0f, 0.0f), 127.0f);  // ye
        lines[line] = ep;
    } else {
        int pix = tid - PREP_TRANS - NLINES;     // 0 .. 16383
        int y = pix >> 7, x = pix & 127;
        float a = jloc[pix];
        float m = a;
        #pragma unroll
        for (int dy = -1; dy <= 1; dy++) {
            #pragma unroll
            for (int dx = -1; dx <= 1; dx++) {
                int yy = y + dy, xx = x + dx;
                if (yy >= 0 && yy < HPX && xx >= 0 && xx < WPX) {
                    m = fmaxf(m, jloc[yy * WPX + xx]);
                }
            }
        }
        unsigned long long kk = 0ull;
        if (a == m && a > 0.0f) {
            kk = ((unsigned long long)__float_as_uint(a) << 32)
               | (unsigned long long)(0xFFFFFFFFu - (unsigned int)pix);
        }
        keys_full[pix] = kk;
    }
}

// ---------------------------------------------------------------------------
// Single-block top-k v3: build survivor histogram in LDS from keys_full,
// hierarchical suffix scan (registers + wave shfl, ~7 barriers total vs 27),
// threshold bin T, compact candidates (bin >= T), rank-based selection
// (unique keys => rank is a bijection => direct write to slot r).
// ---------------------------------------------------------------------------
__global__ __launch_bounds__(1024) void select_topk(
        const unsigned long long* __restrict__ keys_full,
        const float* __restrict__ joff,
        float* __restrict__ junc, float* __restrict__ scores, int topk) {
    __shared__ unsigned int h[NBINS];            // 16 KB
    __shared__ unsigned long long cand[CAND];    // 8 KB
    __shared__ unsigned int wt[16];              // wave totals
    __shared__ unsigned int wo[16];              // exclusive-above wave sums
    __shared__ unsigned int scount;
    __shared__ int Ts;
    int t = threadIdx.x;
    int l = t & 63, w = t >> 6;

    #pragma unroll
    for (int r = 0; r < 4; r++) h[t * 4 + r] = 0u;
    if (t == 0) { scount = 0; Ts = 0; }
    __syncthreads();

    // survivor histogram (~1.8k LDS atomics over 4096 bins, low conflict)
    #pragma unroll
    for (int i = 0; i < 16; i++) {
        unsigned long long kk = keys_full[t + i * 1024];
        if (kk) {
            float val = __uint_as_float((unsigned int)(kk >> 32));
            int bin = min(NBINS - 1, (int)(val * (float)NBINS));
            atomicAdd(&h[bin], 1u);
        }
    }
    __syncthreads();

    // thread t owns bins [4t, 4t+3]; serial suffix in registers
    unsigned int h0 = h[4 * t], h1 = h[4 * t + 1],
                 h2 = h[4 * t + 2], h3 = h[4 * t + 3];
    unsigned int s3 = h3, s2 = h2 + s3, s1 = h1 + s2, s0 = h0 + s1;

    // wave inclusive-suffix of per-thread totals (barrier-free shfl)
    unsigned int x = s0;
    #pragma unroll
    for (int off = 1; off < 64; off <<= 1) {
        unsigned int y = __shfl_down(x, off);
        if (l + off < 64) x += y;
    }
    if (l == 0) wt[w] = x;                       // wave total
    __syncthreads();
    if (t < 16) {                                // exclusive-above over 16 waves
        unsigned int acc = 0;
        for (int ww = 15; ww > t; ww--) acc += wt[ww];
        wo[t] = acc;
    }
    __syncthreads();

    // A = sum of totals of all threads > t (suffix value at bin 4t+4)
    unsigned int A  = wo[w] + (x - s0);
    unsigned int S0 = s0 + A, S1 = s1 + A, S2 = s2 + A, S3 = s3 + A;
    unsigned int tku = (unsigned int)topk;
    // unique crossing of the non-increasing suffix through topk
    if (S0 >= tku && S1 < tku) Ts = 4 * t;
    if (S1 >= tku && S2 < tku) Ts = 4 * t + 1;
    if (S2 >= tku && S3 < tku) Ts = 4 * t + 2;
    if (S3 >= tku && A  < tku) Ts = 4 * t + 3;
    __syncthreads();
    int T = Ts;

    // compact candidates with bin >= T (count >= topk, typically topk+~10)
    #pragma unroll
    for (int i = 0; i < 16; i++) {
        unsigned long long kk = keys_full[t + i * 1024];
        if (kk) {
            float val = __uint_as_float((unsigned int)(kk >> 32));
            int bin = min(NBINS - 1, (int)(val * (float)NBINS));
            if (bin >= T) {
                unsigned int p = atomicAdd(&scount, 1u);
                if (p < CAND) cand[p] = kk;
            }
        }
    }
    __syncthreads();
    unsigned int sc = min(scount, (unsigned int)CAND);

    // rank-based selection: slot r = #{cand > mine}; keys unique => bijection
    if (t < (int)sc) {
        unsigned long long k = cand[t];
        int r = 0;
        for (unsigned int j = 0; j < sc; j++) r += (cand[j] > k) ? 1 : 0;
        if (r < topk) {
            float val = __uint_as_float((unsigned int)(k >> 32));
            unsigned int idx = 0xFFFFFFFFu - (unsigned int)(k & 0xFFFFFFFFull);
            if (idx >= HW) idx = 0;              // pad guard (unreachable)
            float xo = joff[idx];
            float yo = joff[HW + idx];
            junc[2 * r]     = (float)(idx & 127) + xo + 0.5f;
            junc[2 * r + 1] = (float)(idx >> 7)  + yo + 0.5f;
            scores[r] = val;
        }
    }
    // pad slots [sc, topk) -- unreachable in practice (sc >= topk by T)
    if (t >= (int)sc && t < topk) {
        junc[2 * t]     = joff[0] + 0.5f;
        junc[2 * t + 1] = joff[HW] + 0.5f;
        scores[t] = 0.0f;
    }
}

// ---------------------------------------------------------------------------
// LOI: one thread = (line, point, channel-quad).
// 4 consecutive lanes (cq=0..3) gather the SAME bilinear corner -> one 64B
// segment per 4 lanes. Non-temporal output stores keep the 167.8 MB stream
// from evicting the 1 MB feat_t working set out of L2.
// At its write floor (~27 us for 167.8 MB) -- proven insensitive to layout.
// ---------------------------------------------------------------------------
__global__ __launch_bounds__(256) void loi_kernel(
        const float4* __restrict__ lines,
        const float4* __restrict__ feat4,     // feat_t viewed as float4[pix*4+cq]
        float* __restrict__ out) {
    int tid  = blockIdx.x * 256 + threadIdx.x;   // 0 .. 10,485,759
    int cq   = tid & 3;                          // channel quad 0..3
    int p    = (tid >> 2) & 31;                  // sample point 0..31
    int line = tid >> 7;                         // 0 .. 81919

    float4 ep = lines[line];                     // broadcast within wave

    float tk = (float)p * (1.0f / 31.0f);
    float px = ep.x * tk + ep.z * (1.0f - tk) - 0.5f;
    float py = ep.y * tk + ep.w * (1.0f - tk) - 0.5f;

    float px0 = fminf(fmaxf(floorf(px), 0.0f), 127.0f);
    float py0 = fminf(fmaxf(floorf(py), 0.0f), 127.0f);
    float px1 = fminf(px0 + 1.0f, 127.0f);
    float py1 = fminf(py0 + 1.0f, 127.0f);

    float wx1 = px - px0, wx0 = px1 - px;
    float wy1 = py - py0, wy0 = py1 - py;
    float w00 = wy0 * wx0, w01 = wy0 * wx1;
    float w10 = wy1 * wx0, w11 = wy1 * wx1;

    int r0 = ((int)py0) * WPX;
    int r1 = ((int)py1) * WPX;
    int c0 = (int)px0;
    int c1 = (int)px1;

    float4 a = feat4[(r0 + c0) * 4 + cq];
    float4 b = feat4[(r0 + c1) * 4 + cq];
    float4 c = feat4[(r1 + c0) * 4 + cq];
    float4 d = feat4[(r1 + c1) * 4 + cq];

    float v0 = a.x * w00 + b.x * w01 + c.x * w10 + d.x * w11;
    float v1 = a.y * w00 + b.y * w01 + c.y * w10 + d.y * w11;
    float v2 = a.z * w00 + b.z * w01 + c.z * w10 + d.z * w11;
    float v3 = a.w * w00 + b.w * w01 + c.w * w10 + d.w * w11;

    // out[line*512 + c*32 + p], c = cq*4 + j.  Per store instruction a wave
    // covers 4 full 64B segments (16 lanes x 4B contiguous per cq group).
    float* ob = out + (size_t)line * 512 + cq * 128 + p;
    __builtin_nontemporal_store(v0, ob);
    __builtin_nontemporal_store(v1, ob + 32);
    __builtin_nontemporal_store(v2, ob + 64);
    __builtin_nontemporal_store(v3, ob + 96);
}

extern "C" void kernel_launch(void* const* d_in, const int* in_sizes, int n_in,
                              void* d_out, int out_size, void* d_ws, size_t ws_size,
                              hipStream_t stream) {
    const float* md   = (const float*)d_in[0];
    const float* dis  = (const float*)d_in[1];
    const float* res  = (const float*)d_in[2];
    const float* feat = (const float*)d_in[3];
    const float* jloc = (const float*)d_in[4];
    const float* joff = (const float*)d_in[5];
    int topk = (out_size - LOI_SIZE) / 3;

    char* ws = (char*)d_ws;
    float* feat_t                 = (float*)(ws + FEAT_T_OFF);
    float4* lines                 = (float4*)(ws + LINES_OFF);
    unsigned long long* keys_full = (unsigned long long*)(ws + KEYS_OFF);

    float* out    = (float*)d_out;
    float* junc   = out + LOI_SIZE;
    float* scores = junc + 2 * topk;

    // 3 dispatches total (was 4)
    prep_kernel <<<PREP_TOTAL / 256, 256, 0, stream>>>(
                    feat, feat_t, md, dis, res, lines, jloc, keys_full);
    select_topk <<<1, 1024, 0, stream>>>(keys_full, joff, junc, scores, topk);
    loi_kernel  <<<(NLINES * 128) / 256, 256, 0, stream>>>(
                    lines, (const float4*)feat_t, out);
}